// Round 8
// baseline (177.320 us; speedup 1.0000x reference)
//
#include <hip/hip_runtime.h>
#include <stdint.h>

// Keep IoU arithmetic bit-identical to an IEEE no-FMA reference:
#pragma clang fp contract(off)

#define BB   8
#define NN   2048
#define CC   32
#define WORDS 64           // uint32 words per 2048-bit row mask
#define NBLK 64            // rank blocks of 32
#define NMS_THR 0.45f
#define PRE_THR 0.005f
#define PADI(i) ((((i) >> 5) * 33) + ((i) & 31))   // padded SoA index
#define KPAD(i) ((i) + ((i) >> 4))                 // u64 key pad

typedef unsigned long long u64;

// ---------------- K1: per-image adjacency bitmask ----------------
__global__ __launch_bounds__(256) void adj_kernel(const float* __restrict__ bbs,
                                                  uint32_t* __restrict__ adj) {
    __shared__ float sx1[2112], sy1[2112], sx2[2112], sy2[2112];
    const int b = blockIdx.y;
    const int t = threadIdx.x;
    const float4* bp = (const float4*)bbs + (size_t)b * NN;
    for (int i = t; i < NN; i += 256) {
        float4 v = bp[i];
        int p = PADI(i);
        sx1[p] = v.x; sy1[p] = v.y; sx2[p] = v.z; sy2[p] = v.w;
    }
    __syncthreads();

    const int wave = t >> 6, lane = t & 63;
    const int row0 = blockIdx.x * 16 + wave * 4;
    const float THI = 0.45f * 1.00002f;
    const float TLO = 0.45f * 0.99998f;

    float ax1[4], ay1[4], ax2[4], ay2[4], areaA[4];
#pragma unroll
    for (int r = 0; r < 4; ++r) {
        int p = PADI(row0 + r);
        ax1[r] = sx1[p]; ay1[r] = sy1[p]; ax2[r] = sx2[p]; ay2[r] = sy2[p];
        areaA[r] = (ax2[r] - ax1[r]) * (ay2[r] - ay1[r]);
    }
    uint32_t w[4] = {0, 0, 0, 0};
#pragma unroll 4
    for (int j = 0; j < 32; ++j) {
        int p = lane * 33 + j;                 // bank (lane+j)%32: 2-way = free
        float bx1 = sx1[p], by1 = sy1[p], bx2 = sx2[p], by2 = sy2[p];
        float areaB = (bx2 - bx1) * (by2 - by1);
#pragma unroll
        for (int r = 0; r < 4; ++r) {
            float ltx = fmaxf(ax1[r], bx1), lty = fmaxf(ay1[r], by1);
            float rbx = fminf(ax2[r], bx2), rby = fminf(ay2[r], by2);
            float ww = fmaxf(rbx - ltx, 0.0f);
            float hh = fmaxf(rby - lty, 0.0f);
            float inter = ww * hh;
            float uni  = (areaA[r] + areaB) - inter;
            float unim = fmaxf(uni, 1e-12f);
            float q1 = inter * __builtin_amdgcn_rcpf(unim);
            bool hi = q1 > THI;
            bool lo = q1 < TLO;
            bool adjb;
            if (__builtin_expect(__any((int)!(hi || lo)), 0))
                adjb = (inter / unim) > NMS_THR;   // exact IEEE div, rare
            else
                adjb = hi;
            if (adjb) w[r] |= (1u << j);
        }
    }
#pragma unroll
    for (int r = 0; r < 4; ++r) {
        int row = row0 + r;
        uint32_t dmask = (lane == (row >> 5)) ? ~(1u << (row & 31)) : 0xFFFFFFFFu;
        adj[((size_t)b * NN + row) * WORDS + lane] = w[r] & dmask;
    }
}

// ---------------- K2: per-(b,c) bitonic sort, 1024 threads ----------------
__device__ __forceinline__ void ce_reg(u64& a, u64& b, bool up) {
    u64 mn = (a < b) ? a : b;
    u64 mx = (a < b) ? b : a;
    a = up ? mx : mn;
    b = up ? mn : mx;
}

__global__ __launch_bounds__(1024) void sort_kernel(const float* __restrict__ conf,
                                                    uint32_t* __restrict__ wsOrd) {
    __shared__ u64 keys[2176];   // KPAD(2047)=2174
    const int bc = blockIdx.x;
    const int t  = threadIdx.x;
    const float* cf = conf + (size_t)bc * NN;

    if (t < 512) {
        const int g = 4 * t;
        float4 v = ((const float4*)cf)[t];
        float f0 = (v.x > PRE_THR) ? v.x : 0.0f;
        float f1 = (v.y > PRE_THR) ? v.y : 0.0f;
        float f2 = (v.z > PRE_THR) ? v.z : 0.0f;
        float f3 = (v.w > PRE_THR) ? v.w : 0.0f;
        u64 a0 = ((u64)__float_as_uint(f0) << 32) | (uint32_t)(NN - 1 - (g + 0));
        u64 a1 = ((u64)__float_as_uint(f1) << 32) | (uint32_t)(NN - 1 - (g + 1));
        u64 a2 = ((u64)__float_as_uint(f2) << 32) | (uint32_t)(NN - 1 - (g + 2));
        u64 a3 = ((u64)__float_as_uint(f3) << 32) | (uint32_t)(NN - 1 - (g + 3));
        ce_reg(a0, a1, true);
        ce_reg(a2, a3, false);
        bool up4 = ((g & 4) == 0);
        ce_reg(a0, a2, up4); ce_reg(a1, a3, up4);
        ce_reg(a0, a1, up4); ce_reg(a2, a3, up4);
        keys[KPAD(g + 0)] = a0; keys[KPAD(g + 1)] = a1;
        keys[KPAD(g + 2)] = a2; keys[KPAD(g + 3)] = a3;
    }
    __syncthreads();

    for (unsigned k = 8; k <= NN; k <<= 1) {
        unsigned j = k >> 1;
        while (j >= 2) {
            const unsigned h = j >> 1;
            if (t < 512) {
                unsigned g  = (((unsigned)t & ~(h - 1)) << 2) | ((unsigned)t & (h - 1));
                bool up = ((g & k) == 0);
                u64 e0 = keys[KPAD(g)];
                u64 e1 = keys[KPAD(g + h)];
                u64 e2 = keys[KPAD(g + j)];
                u64 e3 = keys[KPAD(g + j + h)];
                ce_reg(e0, e2, up); ce_reg(e1, e3, up);
                ce_reg(e0, e1, up); ce_reg(e2, e3, up);
                keys[KPAD(g)]         = e0;
                keys[KPAD(g + h)]     = e1;
                keys[KPAD(g + j)]     = e2;
                keys[KPAD(g + j + h)] = e3;
            }
            __syncthreads();
            j >>= 2;
        }
        if (j == 1) {
            unsigned i  = (unsigned)t << 1;
            bool up = ((i & k) == 0);
            u64 a = keys[KPAD(i)], d = keys[KPAD(i + 1)];
            ce_reg(a, d, up);
            keys[KPAD(i)] = a; keys[KPAD(i + 1)] = d;
            __syncthreads();
        }
    }

    uint32_t* ov = wsOrd + (size_t)bc * NN;
    for (int r = t; r < NN; r += 1024) {
        u64 kk = keys[KPAD(r)];
        uint32_t idx = (uint32_t)(NN - 1) - (uint32_t)(kk & 0xffffffffu);
        uint32_t nz  = ((uint32_t)(kk >> 32) != 0u) ? 0x10000u : 0u;
        ov[r] = idx | nz;
    }
}

// ---------------- K3: rank-space sub-adjacency extraction ----------------
__global__ __launch_bounds__(256) void extract_kernel(const uint32_t* __restrict__ adj,
                                                      const uint32_t* __restrict__ wsOrd,
                                                      uint32_t* __restrict__ wsM) {
    const int blkid = blockIdx.x;
    const int bc = blkid >> 3, chunk = blkid & 7;
    const int b  = bc >> 5;
    const int t = threadIdx.x, wv = t >> 6, lane = t & 63, e = lane & 31, h = lane >> 5;
    const uint32_t* ov = wsOrd + (size_t)bc * NN;
    const uint32_t* ab = adj + (size_t)b * NN * WORDS;

    for (int blk = chunk * 8 + wv; blk < chunk * 8 + 8; blk += 4) {
        uint32_t ue = ov[blk * 32 + e];
        int widx = (int)((ue & 0xffffu) >> 5);
        int bpos = (int)(ue & 31u);
        uint32_t wb[16];
#pragma unroll
        for (int k = 0; k < 16; ++k) {
            uint32_t ud = ov[blk * 32 + k * 2 + h] & 0xffffu;
            wb[k] = ab[(size_t)ud * WORDS + widx];
        }
        uint32_t vM = 0;
#pragma unroll
        for (int k = 0; k < 16; ++k) {
            unsigned long long bal = __ballot(((wb[k] >> bpos) & 1u) != 0u);
            vM = (lane == 2 * k    ) ? (uint32_t)bal         : vM;
            vM = (lane == 2 * k + 1) ? (uint32_t)(bal >> 32) : vM;
        }
        if (lane < 32)
            wsM[(size_t)bc * NN + blk * 32 + lane] = vM & (0xFFFFFFFEu << lane);
    }
}

// ---------------- K4: register-resident serial scan + output ----------------
// One wave per (b,c). Rows ping-pong in registers (launch_bounds(64,1) lifts the
// occupancy-driven VGPR cap that spilled the R5 version). ord/M staged in LDS.
#define PREFETCH_ROWS(u_, r_)                                          \
  {                                                                    \
    _Pragma("unroll")                                                  \
    for (int d = 0; d < 32; ++d) {                                     \
      int ud_ = __builtin_amdgcn_readlane((int)(u_), d) & 0xffff;      \
      r_[d] = rowp[(size_t)ud_ * WORDS];                               \
    }                                                                  \
  }

#define RESOLVE(u_, m_, r_)                                            \
  {                                                                    \
    int wq_ = (int)((((u_) & 0xffffu) >> 5) << 2);                     \
    int pm_ = __builtin_amdgcn_ds_bpermute(wq_, (int)S);               \
    bool a0_ = ((((u_) >> 16) & 1u) != 0u) &&                          \
               (((pm_ >> ((u_) & 31u)) & 1) == 0);                     \
    uint32_t alive_ = (uint32_t)__ballot((int)a0_);                    \
    _Pragma("unroll")                                                  \
    for (int d = 0; d < 32; ++d) {                                     \
      uint32_t md_ = (uint32_t)__builtin_amdgcn_readlane((int)(m_), d);\
      alive_ = (alive_ & (1u << d)) ? (alive_ & ~md_) : alive_;        \
    }                                                                  \
    uint32_t acc_ = 0;                                                 \
    _Pragma("unroll")                                                  \
    for (int d = 0; d < 32; ++d)                                       \
      acc_ |= (alive_ & (1u << d)) ? r_[d] : 0u;                       \
    S |= acc_;                                                         \
  }

__global__ __launch_bounds__(64, 1) void scan_kernel(const float* __restrict__ conf,
                                                     const uint32_t* __restrict__ adj,
                                                     const uint32_t* __restrict__ wsOrd,
                                                     const uint32_t* __restrict__ wsM,
                                                     float* __restrict__ out) {
    __shared__ uint32_t ordL[NN];   // 8 KB
    __shared__ uint32_t Ml[NN];     // 8 KB (pre-masked M')
    __shared__ uint32_t Sarr[WORDS];
    const int bc = blockIdx.x;
    const int b  = bc >> 5;
    const int lane = threadIdx.x;
    const uint32_t* ov = wsOrd + (size_t)bc * NN;
    const uint32_t* mv = wsM   + (size_t)bc * NN;
    const uint32_t* const rowp = adj + (size_t)b * NN * WORDS + lane;
    const float* cf = conf + (size_t)bc * NN;
    float* op = out + (size_t)bc * NN;

    // Stage ord + M into LDS (uint4-wide, coalesced).
    for (int i = lane; i < NN / 4; i += 64) {
        ((uint4*)ordL)[i] = ((const uint4*)ov)[i];
        ((uint4*)Ml)[i]   = ((const uint4*)mv)[i];
    }
    __syncthreads();

    uint32_t S = 0;
    uint32_t rA[32], rB[32];
    uint32_t uA = ordL[lane & 31],        mA = Ml[lane & 31];
    uint32_t uB = ordL[32 + (lane & 31)], mB = Ml[32 + (lane & 31)];
    PREFETCH_ROWS(uA, rA);
    PREFETCH_ROWS(uB, rB);

    for (int blk = 0; blk < NBLK; blk += 2) {
        // -- consume blk (A-buffer); refill A with blk+2 under B's resolve --
        uint32_t uN = 0, mN = 0;
        if (blk + 2 < NBLK) {
            uN = ordL[(blk + 2) * 32 + (lane & 31)];
            mN = Ml[(blk + 2) * 32 + (lane & 31)];
        }
        RESOLVE(uA, mA, rA);
        if (blk + 2 < NBLK) { uA = uN; mA = mN; PREFETCH_ROWS(uA, rA); }

        // -- consume blk+1 (B-buffer); refill B with blk+3 --
        uint32_t uN2 = 0, mN2 = 0;
        if (blk + 3 < NBLK) {
            uN2 = ordL[(blk + 3) * 32 + (lane & 31)];
            mN2 = Ml[(blk + 3) * 32 + (lane & 31)];
        }
        RESOLVE(uB, mB, rB);
        if (blk + 3 < NBLK) { uB = uN2; mB = mN2; PREFETCH_ROWS(uB, rB); }
    }

    Sarr[lane] = S;
    __syncthreads();

    // Output: float4 per lane per iter (1 KB/wave-load), sup bits from Sarr.
#pragma unroll
    for (int it = 0; it < 8; ++it) {
        int i4 = it * 256 + lane * 4;           // first element index of this float4
        float4 v = ((const float4*)cf)[it * 64 + lane];
        uint32_t sw = Sarr[i4 >> 5];            // all 4 bits live in this word
        float4 o;
        o.x = (v.x > PRE_THR && !((sw >> ((i4 + 0) & 31)) & 1u)) ? v.x : 0.0f;
        o.y = (v.y > PRE_THR && !((sw >> ((i4 + 1) & 31)) & 1u)) ? v.y : 0.0f;
        o.z = (v.z > PRE_THR && !((sw >> ((i4 + 2) & 31)) & 1u)) ? v.z : 0.0f;
        o.w = (v.w > PRE_THR && !((sw >> ((i4 + 3) & 31)) & 1u)) ? v.w : 0.0f;
        ((float4*)op)[it * 64 + lane] = o;
    }
}

// ---------------- Fallback (ws too small): monolithic ----------------
__global__ __launch_bounds__(256) void nms_fallback(const float* __restrict__ conf,
                                                    const uint32_t* __restrict__ adj,
                                                    float* __restrict__ out) {
    __shared__ unsigned long long keys[NN];
    __shared__ uint32_t ordv[NN];
    __shared__ uint32_t Mlds[NBLK * 32];
    __shared__ uint32_t Sarr[WORDS];
    const int bc = blockIdx.x;
    const int b  = bc >> 5;
    const int t  = threadIdx.x;
    const float* cf = conf + (size_t)bc * NN;
    const uint32_t* const abase = adj + (size_t)b * NN * WORDS;

    for (int i = t; i < NN; i += 256) {
        float v  = cf[i];
        float vt = (v > PRE_THR) ? v : 0.0f;
        keys[i] = ((unsigned long long)__float_as_uint(vt) << 32) | (uint32_t)(NN - 1 - i);
    }
    __syncthreads();
    for (unsigned k = 2; k <= NN; k <<= 1)
        for (unsigned j = k >> 1; j > 0; j >>= 1) {
            for (unsigned p = t; p < NN / 2; p += 256) {
                unsigned i  = ((p & ~(j - 1)) << 1) | (p & (j - 1));
                unsigned ij = i | j;
                unsigned long long a = keys[i], d = keys[ij];
                bool up = ((i & k) == 0);
                if (up ? (a < d) : (a > d)) { keys[i] = d; keys[ij] = a; }
            }
            __syncthreads();
        }
    for (int r = t; r < NN; r += 256) {
        unsigned long long kk = keys[r];
        uint32_t idx = (uint32_t)(NN - 1) - (uint32_t)(kk & 0xffffffffu);
        uint32_t nz  = ((uint32_t)(kk >> 32) != 0u) ? 0x10000u : 0u;
        ordv[r] = idx | nz;
    }
    __syncthreads();
    {
        const int wid = t >> 6, lane = t & 63, e = lane & 31, h = lane >> 5;
        for (int blk = wid * 16; blk < wid * 16 + 16; ++blk) {
            uint32_t ue = ordv[blk * 32 + e];
            int widx = (int)((ue & 0xffffu) >> 5);
            int bpos = (int)(ue & 31u);
            uint32_t vM = 0;
#pragma unroll
            for (int half = 0; half < 2; ++half) {
                uint32_t wbuf[8];
#pragma unroll
                for (int k = 0; k < 8; ++k) {
                    int d = half * 16 + k * 2 + h;
                    uint32_t ud = ordv[blk * 32 + d] & 0xffffu;
                    wbuf[k] = abase[(size_t)ud * WORDS + widx];
                }
#pragma unroll
                for (int k = 0; k < 8; ++k) {
                    int d0 = half * 16 + k * 2;
                    unsigned long long bal = __ballot(((wbuf[k] >> bpos) & 1u) != 0u);
                    vM = (lane == d0    ) ? (uint32_t)bal         : vM;
                    vM = (lane == d0 + 1) ? (uint32_t)(bal >> 32) : vM;
                }
            }
            if (lane < 32) Mlds[blk * 32 + lane] = vM;
        }
    }
    __syncthreads();
    if (t < 64) {
        const int lane = t;
        const uint32_t* const rowp = abase + lane;
        uint32_t S = 0;
        uint32_t rbA[32], rbB[32];
        uint32_t u_c, m_c, u_n, m_n;
        u_c = ordv[lane & 31];
        m_c = Mlds[lane & 31];
#pragma unroll
        for (int d = 0; d < 32; ++d) {
            int ud = __builtin_amdgcn_readlane((int)u_c, d) & 0xffff;
            rbA[d] = rowp[(size_t)ud * WORDS];
        }
        auto do_block = [&](int blk, uint32_t (&rbC)[32], uint32_t (&rbN)[32]) {
            u_n = 0; m_n = 0;
            if (blk < 63) {
                u_n = ordv[(blk + 1) * 32 + (lane & 31)];
                m_n = Mlds[(blk + 1) * 32 + (lane & 31)];
#pragma unroll
                for (int d = 0; d < 32; ++d) {
                    int ud = __builtin_amdgcn_readlane((int)u_n, d) & 0xffff;
                    rbN[d] = rowp[(size_t)ud * WORDS];
                }
            }
            int wq  = (int)(((u_c & 0xffffu) >> 5) << 2);
            int bpv = (int)(u_c & 31u);
            int pm  = __builtin_amdgcn_ds_bpermute(wq, (int)S);
            bool a0 = (((u_c >> 16) & 1u) != 0u) && (((pm >> bpv) & 1) == 0);
            uint32_t alive = (uint32_t)__ballot((int)a0);
#pragma unroll
            for (int d = 0; d < 32; ++d) {
                uint32_t rowd = (uint32_t)__builtin_amdgcn_readlane((int)m_c, d);
                uint32_t mk = rowd & (0xFFFFFFFEu << d);
                alive = (alive & (1u << d)) ? (alive & ~mk) : alive;
            }
            uint32_t acc = 0;
#pragma unroll
            for (int d = 0; d < 32; ++d)
                acc |= (alive & (1u << d)) ? rbC[d] : 0u;
            S |= acc;
            u_c = u_n; m_c = m_n;
        };
        for (int blk = 0; blk < 64; blk += 2) {
            do_block(blk,     rbA, rbB);
            do_block(blk + 1, rbB, rbA);
        }
        Sarr[lane] = S;
    }
    __syncthreads();
    float* op = out + (size_t)bc * NN;
    for (int i = t; i < NN; i += 256) {
        float v = cf[i];
        bool sup = (Sarr[i >> 5] >> (i & 31)) & 1u;
        op[i] = (v > PRE_THR && !sup) ? v : 0.0f;
    }
}

extern "C" void kernel_launch(void* const* d_in, const int* in_sizes, int n_in,
                              void* d_out, int out_size, void* d_ws, size_t ws_size,
                              hipStream_t stream) {
    const float* bbs  = (const float*)d_in[0];   // [8,2048,4]
    const float* conf = (const float*)d_in[1];   // [8,32,2048]
    float* out = (float*)d_out;                  // [8,32,2048]

    const size_t adjB = (size_t)BB * NN * WORDS * sizeof(uint32_t);   // 4 MB
    const size_t ordB = (size_t)BB * CC * NN * sizeof(uint32_t);      // 2 MB
    const size_t mB   = ordB;                                          // 2 MB
    uint32_t* adj = (uint32_t*)d_ws;

    if (ws_size >= adjB + ordB + mB) {
        uint32_t* wsOrd = (uint32_t*)((char*)d_ws + adjB);
        uint32_t* wsM   = (uint32_t*)((char*)d_ws + adjB + ordB);
        adj_kernel    <<<dim3(NN / 16, BB), 256, 0, stream>>>(bbs, adj);
        sort_kernel   <<<BB * CC, 1024, 0, stream>>>(conf, wsOrd);
        extract_kernel<<<BB * CC * 8, 256, 0, stream>>>(adj, wsOrd, wsM);
        scan_kernel   <<<BB * CC, 64, 0, stream>>>(conf, adj, wsOrd, wsM, out);
    } else if (ws_size >= adjB) {
        adj_kernel  <<<dim3(NN / 16, BB), 256, 0, stream>>>(bbs, adj);
        nms_fallback<<<BB * CC, 256, 0, stream>>>(conf, adj, out);
    }
}